// Round 6
// baseline (289.782 us; speedup 1.0000x reference)
//
#include <hip/hip_runtime.h>
#include <hip/hip_bf16.h>

#define BTC 16
#define NC 1024
#define DC 128
#define HC 8
#define HDC 16

typedef __attribute__((ext_vector_type(8)))  short bf16x8;   // 8 bf16 = 4 VGPR
typedef __attribute__((ext_vector_type(4)))  float f32x4;    // 16x16 C/D frag
typedef __attribute__((ext_vector_type(16))) float f32x16;   // 32x32 C/D frag
typedef __attribute__((ext_vector_type(4)))  short short4v;  // 8B pack

#if __has_builtin(__builtin_amdgcn_exp2f)
#define EXP2F(x) __builtin_amdgcn_exp2f(x)
#else
#define EXP2F(x) exp2f(x)
#endif

// q scale: 0.25 (1/sqrt(HD)) * log2(e) -> attention uses exp2 directly
#define QSCALE 0.36067376022224085f

union PK2 { short4v s4; __hip_bfloat162 h2[2]; };
union PK8 { bf16x8 v; short s[8]; __hip_bfloat162 h2[4]; };

static __device__ inline short f2bf(float f) {               // RNE f32->bf16
    unsigned u = __builtin_bit_cast(unsigned, f);
    u += 0x7fffu + ((u >> 16) & 1u);
    return (short)(u >> 16);
}

static __device__ inline bf16x8 pack8f(float4 a, float4 b) {
    PK8 f;
    f.h2[0] = __float22bfloat162_rn(make_float2(a.x, a.y));
    f.h2[1] = __float22bfloat162_rn(make_float2(a.z, a.w));
    f.h2[2] = __float22bfloat162_rn(make_float2(b.x, b.y));
    f.h2[3] = __float22bfloat162_rn(make_float2(b.z, b.w));
    return f.v;
}

// ---------------- qkv projection, fp32 in, bf16 out, LDS-free MFMA ----------
// (unchanged from R5 — passed, not the bottleneck)
__global__ __launch_bounds__(256)
void proj_qkv(const float* __restrict__ x,
              const float* __restrict__ Wq, const float* __restrict__ bq,
              const float* __restrict__ Wk, const float* __restrict__ bk,
              const float* __restrict__ Wv, const float* __restrict__ bv,
              short* __restrict__ qo, short* __restrict__ ko, short* __restrict__ vto)
{
    const int y = blockIdx.y;
    const float* W    = (y == 0) ? Wq : (y == 1) ? Wk : Wv;
    const float* bias = (y == 0) ? bq : (y == 1) ? bk : bv;
    const float scale = (y == 0) ? QSCALE : 1.0f;

    const int tid  = threadIdx.x;
    const int wave = tid >> 6;
    const int lane = tid & 63;
    const int l15  = lane & 15;
    const int quad = lane >> 4;
    const int rowA = blockIdx.x * 64 + wave * 16;

    f32x4 acc[8];
#pragma unroll
    for (int t = 0; t < 8; ++t) acc[t] = (f32x4){0.f, 0.f, 0.f, 0.f};

#pragma unroll
    for (int kk = 0; kk < DC; kk += 32) {
        const float* xp = &x[(size_t)(rowA + l15) * DC + kk + quad * 8];
        bf16x8 Af = pack8f(*(const float4*)xp, *(const float4*)(xp + 4));
#pragma unroll
        for (int t = 0; t < 8; ++t) {
            const float* wp = &W[(size_t)(t * 16 + l15) * DC + kk + quad * 8];
            bf16x8 Bf = pack8f(*(const float4*)wp, *(const float4*)(wp + 4));
            acc[t] = __builtin_amdgcn_mfma_f32_16x16x32_bf16(Af, Bf, acc[t], 0, 0, 0);
        }
    }

#pragma unroll
    for (int t = 0; t < 8; ++t) {
        int c = t * 16 + l15;
        float b = bias[c];
#pragma unroll
        for (int r = 0; r < 4; ++r) {
            int row = rowA + quad * 4 + r;
            float val = (acc[t][r] + b) * scale;
            if (y == 2)
                vto[(size_t)(row >> 10) * (DC * NC) + (size_t)c * NC + (row & (NC - 1))] = f2bf(val);
            else
                ((y == 0) ? qo : ko)[(size_t)row * DC + c] = f2bf(val);
        }
    }
}

// ---------------- fused attention + output projection -----------------------
// block = 1024 thr = 16 waves = (8 heads x 2 key-halves); 32 q-rows.
// grid (32 qtiles, 16 bt) = 512 blocks = exactly 2 blocks/CU (32 waves/CU).
// NO __syncthreads in the main loop: adj is read straight from global (8-way
// L1/L2-shared across head-waves), P round-trips through wave-private
// XOR-swizzled LDS (conflict-free b64 writes / b128 reads).
// Per 32-key jj: S^T = K·Q^T (one mfma_32x32x16); P=exp2(S)·adj -> bf16;
// ctx += P·V (one mfma_16x16x32 per 16-row half); w accumulated in VALU.
// Epilogue: key-half reduction via LDS, divide, then block-local
// out = ctx @ Wo^T + bo on 16 wave-tiles.
__global__ __launch_bounds__(1024, 8)
void attn_fused(const short* __restrict__ qb, const short* __restrict__ kb,
                const short* __restrict__ vt, const float* __restrict__ adj,
                const float* __restrict__ Wo, const float* __restrict__ bo,
                float* __restrict__ out)
{
    __shared__ short Ps[16][32 * 40];    // wave-private P scratch, 41 KB
    __shared__ float Rs[HC][32][17];     // khalf=1 ctx partials, 17.4 KB
    __shared__ float Ws[2][HC][32];      // w partials, 2 KB
    __shared__ short Cs[32 * 136];       // ctx staging for out-proj, 8.7 KB

    const int tid   = threadIdx.x;
    const int wave  = tid >> 6;
    const int lane  = tid & 63;
    const int l15   = lane & 15;
    const int quad  = lane >> 4;
    const int l31   = lane & 31;
    const int lh    = lane >> 5;
    const int h     = wave & 7;
    const int khalf = wave >> 3;
    const int bt    = blockIdx.y;
    const int qt0   = blockIdx.x * 32;

    const size_t xb = (size_t)bt * NC * DC;
    const size_t ab = (size_t)bt * NC * NC;

    // Q B-frag for 32x32x16: B[n=q=l31][k=d=lh*8+j] (QSCALE folded at proj)
    bf16x8 Bq = *(const bf16x8*)&qb[xb + (size_t)(qt0 + l31) * DC + h * HDC + lh * 8];

    f32x4 Cc[2];
    Cc[0] = (f32x4){0.f, 0.f, 0.f, 0.f};
    Cc[1] = (f32x4){0.f, 0.f, 0.f, 0.f};
    float wacc = 0.f;

    short* Pw = &Ps[wave][0];
    const int sw_w = (l31 >> 3) & 3;                 // write-side XOR swizzle
    const f32x16 z16 = {0.f,0.f,0.f,0.f,0.f,0.f,0.f,0.f,
                        0.f,0.f,0.f,0.f,0.f,0.f,0.f,0.f};

    const short* kbase = &kb[xb + h * HDC + lh * 8];
    const short* vbase = &vt[((size_t)bt * DC + h * HDC + l15) * NC];
    const float* abase = &adj[ab + (size_t)(qt0 + l31) * NC + 4 * lh];

    for (int jj = 0; jj < 16; ++jj) {
        const int jt = khalf * 512 + jj * 32;

        // issue all loads up front (no deps between them)
        bf16x8 Kf = *(const bf16x8*)&kbase[(size_t)(jt + l31) * DC];
        bf16x8 Vf = *(const bf16x8*)&vbase[jt + quad * 8];
        float4 a4[4];
#pragma unroll
        for (int rr = 0; rr < 4; ++rr)
            a4[rr] = *(const float4*)&abase[jt + 8 * rr];

        f32x16 S = __builtin_amdgcn_mfma_f32_32x32x16_bf16(Kf, Bq, z16, 0, 0, 0);

        // P^T = exp2(S^T)*adj -> bf16 -> swizzled wave-private LDS [q][key]
#pragma unroll
        for (int rr = 0; rr < 4; ++rr) {
            float p0 = EXP2F(S[4 * rr + 0]) * a4[rr].x;
            float p1 = EXP2F(S[4 * rr + 1]) * a4[rr].y;
            float p2 = EXP2F(S[4 * rr + 2]) * a4[rr].z;
            float p3 = EXP2F(S[4 * rr + 3]) * a4[rr].w;
            wacc += (p0 + p1) + (p2 + p3);
            PK2 pk;
            pk.h2[0] = __float22bfloat162_rn(make_float2(p0, p1));
            pk.h2[1] = __float22bfloat162_rn(make_float2(p2, p3));
            *(short4v*)&Pw[l31 * 40 + (rr ^ sw_w) * 8 + lh * 4] = pk.s4;
        }
        __builtin_amdgcn_wave_barrier();

        // PV: A[m=q(16)=l15][k=key=quad*8+j], swizzled read
#pragma unroll
        for (int s = 0; s < 2; ++s) {
            int R = s * 16 + l15;
            bf16x8 Ap = *(const bf16x8*)&Pw[R * 40 + (quad ^ ((R >> 3) & 3)) * 8];
            Cc[s] = __builtin_amdgcn_mfma_f32_16x16x32_bf16(Ap, Vf, Cc[s], 0, 0, 0);
        }
        __builtin_amdgcn_wave_barrier();
    }

    // ---- epilogue: key-half + lane-half reductions ----
    wacc += __shfl_xor(wacc, 32, 64);            // sum the two lh halves
    if (lane < 32) Ws[khalf][h][l31] = wacc;
    if (khalf == 1) {
#pragma unroll
        for (int s = 0; s < 2; ++s)
#pragma unroll
            for (int r = 0; r < 4; ++r)
                Rs[h][s * 16 + quad * 4 + r][l15] = Cc[s][r];
    }
    __syncthreads();

    if (khalf == 0) {
#pragma unroll
        for (int s = 0; s < 2; ++s)
#pragma unroll
            for (int r = 0; r < 4; ++r) {
                int row = s * 16 + quad * 4 + r;
                float num = Cc[s][r] + Rs[h][row][l15];
                float den = Ws[0][h][row] + Ws[1][h][row];
                float rcp = den > 0.f ? 1.f / den : 0.f;
                Cs[row * 136 + h * HDC + l15] = f2bf(num * rcp);
            }
    }
    __syncthreads();

    // ---- fused out-projection: out(32x128) = ctx(32x128) @ Wo^T + bo -------
    // 16 wave-tiles: wave w -> rows0 = (w&1)*16, col tile t = w>>1
    const int rows0 = (wave & 1) * 16;
    const int t     = wave >> 1;
    f32x4 oacc = (f32x4){0.f, 0.f, 0.f, 0.f};

#pragma unroll
    for (int kk = 0; kk < DC; kk += 32) {
        bf16x8 Ac = *(const bf16x8*)&Cs[(rows0 + l15) * 136 + kk + quad * 8];
        const float* wp = &Wo[(size_t)(t * 16 + l15) * DC + kk + quad * 8];
        bf16x8 Bf = pack8f(*(const float4*)wp, *(const float4*)(wp + 4));
        oacc = __builtin_amdgcn_mfma_f32_16x16x32_bf16(Ac, Bf, oacc, 0, 0, 0);
    }

    {
        int c = t * 16 + l15;
        float b = bo[c];
#pragma unroll
        for (int r = 0; r < 4; ++r) {
            int row = qt0 + rows0 + quad * 4 + r;
            out[((size_t)bt * NC + row) * DC + c] = oacc[r] + b;
        }
    }
}

extern "C" void kernel_launch(void* const* d_in, const int* in_sizes, int n_in,
                              void* d_out, int out_size, void* d_ws, size_t ws_size,
                              hipStream_t stream)
{
    const float* x   = (const float*)d_in[0];
    const float* adj = (const float*)d_in[1];
    const float* Wq  = (const float*)d_in[2];
    const float* bq  = (const float*)d_in[3];
    const float* Wk  = (const float*)d_in[4];
    const float* bk  = (const float*)d_in[5];
    const float* Wv  = (const float*)d_in[6];
    const float* bv  = (const float*)d_in[7];
    const float* Wo  = (const float*)d_in[8];
    const float* bo  = (const float*)d_in[9];
    float* out = (float*)d_out;

    const size_t tok = (size_t)BTC * NC * DC;   // 2,097,152
    short* qbuf = (short*)d_ws;
    short* kbuf = qbuf + tok;
    short* vt   = kbuf + tok;

    dim3 pgrid(256, 3);
    proj_qkv<<<pgrid, 256, 0, stream>>>(x, Wq, bq, Wk, bk, Wv, bv, qbuf, kbuf, vt);

    dim3 agrid(NC / 32, BTC);
    attn_fused<<<agrid, 1024, 0, stream>>>(qbuf, kbuf, vt, adj, Wo, bo, out);
}

// Round 7
// 262.789 us; speedup vs baseline: 1.1027x; 1.1027x over previous
//
#include <hip/hip_runtime.h>
#include <hip/hip_bf16.h>

#define BTC 16
#define NC 1024
#define DC 128
#define HC 8
#define HDC 16

typedef __attribute__((ext_vector_type(8)))  short bf16x8;   // 8 bf16 = 4 VGPR
typedef __attribute__((ext_vector_type(4)))  float f32x4;    // 16x16 C/D frag
typedef __attribute__((ext_vector_type(4)))  short short4v;  // 8B pack

#if __has_builtin(__builtin_amdgcn_exp2f)
#define EXP2F(x) __builtin_amdgcn_exp2f(x)
#else
#define EXP2F(x) exp2f(x)
#endif

// q scale: 0.25 (1/sqrt(HD)) * log2(e) -> attention uses exp2 directly
#define QSCALE 0.36067376022224085f

union PK2 { short4v s4; __hip_bfloat162 h2[2]; };
union PK8 { bf16x8 v; short s[8]; __hip_bfloat162 h2[4]; };

static __device__ inline short f2bf(float f) {               // RNE f32->bf16
    unsigned u = __builtin_bit_cast(unsigned, f);
    u += 0x7fffu + ((u >> 16) & 1u);
    return (short)(u >> 16);
}

static __device__ inline bf16x8 pack8f(float4 a, float4 b) {
    PK8 f;
    f.h2[0] = __float22bfloat162_rn(make_float2(a.x, a.y));
    f.h2[1] = __float22bfloat162_rn(make_float2(a.z, a.w));
    f.h2[2] = __float22bfloat162_rn(make_float2(b.x, b.y));
    f.h2[3] = __float22bfloat162_rn(make_float2(b.z, b.w));
    return f.v;
}

static __device__ inline bf16x8 zero8() {
    PK8 f;
#pragma unroll
    for (int j = 0; j < 8; ++j) f.s[j] = 0;
    return f.v;
}

// ---------------- qkv projection, fp32 in, bf16 out, LDS-free MFMA ----------
// (unchanged — proven, not the bottleneck)
__global__ __launch_bounds__(256)
void proj_qkv(const float* __restrict__ x,
              const float* __restrict__ Wq, const float* __restrict__ bq,
              const float* __restrict__ Wk, const float* __restrict__ bk,
              const float* __restrict__ Wv, const float* __restrict__ bv,
              short* __restrict__ qo, short* __restrict__ ko, short* __restrict__ vto)
{
    const int y = blockIdx.y;
    const float* W    = (y == 0) ? Wq : (y == 1) ? Wk : Wv;
    const float* bias = (y == 0) ? bq : (y == 1) ? bk : bv;
    const float scale = (y == 0) ? QSCALE : 1.0f;

    const int tid  = threadIdx.x;
    const int wave = tid >> 6;
    const int lane = tid & 63;
    const int l15  = lane & 15;
    const int quad = lane >> 4;
    const int rowA = blockIdx.x * 64 + wave * 16;

    f32x4 acc[8];
#pragma unroll
    for (int t = 0; t < 8; ++t) acc[t] = (f32x4){0.f, 0.f, 0.f, 0.f};

#pragma unroll
    for (int kk = 0; kk < DC; kk += 32) {
        const float* xp = &x[(size_t)(rowA + l15) * DC + kk + quad * 8];
        bf16x8 Af = pack8f(*(const float4*)xp, *(const float4*)(xp + 4));
#pragma unroll
        for (int t = 0; t < 8; ++t) {
            const float* wp = &W[(size_t)(t * 16 + l15) * DC + kk + quad * 8];
            bf16x8 Bf = pack8f(*(const float4*)wp, *(const float4*)(wp + 4));
            acc[t] = __builtin_amdgcn_mfma_f32_16x16x32_bf16(Af, Bf, acc[t], 0, 0, 0);
        }
    }

#pragma unroll
    for (int t = 0; t < 8; ++t) {
        int c = t * 16 + l15;
        float b = bias[c];
#pragma unroll
        for (int r = 0; r < 4; ++r) {
            int row = rowA + quad * 4 + r;
            float val = (acc[t][r] + b) * scale;
            if (y == 2)
                vto[(size_t)(row >> 10) * (DC * NC) + (size_t)c * NC + (row & (NC - 1))] = f2bf(val);
            else
                ((y == 0) ? qo : ko)[(size_t)row * DC + c] = f2bf(val);
        }
    }
}

// ---------------- fused attention + output projection -----------------------
// block = 512 thr = 8 waves = 8 heads; 16 q-rows; grid (64 qtiles, 16 bt)
// = 1024 blocks = 4 blocks/CU = 32 waves/CU. NO __syncthreads in the main
// loop: adj read straight from global (all 8 head-waves touch the same 2 KB
// tile -> L1), P round-trips through wave-private LDS only.
// Per 32-key tile jt, per wave:
//   S = K·Q^T : 2x mfma_16x16x32 (d zero-padded 16->32), D[key][q=l15]
//   P = exp2(S)·adj -> bf16 -> wave-private LDS ; w accumulated in VALU
//   ctx += P·V : 1x mfma (V B-frag from transposed vt)
// Epilogue: w quad-reduction (2 shfl + tiny LDS transpose), divide, then
// block-local out(16x128) = ctx(16x128) @ Wo^T + bo.
__global__ __launch_bounds__(512, 8)
void attn_fused(const short* __restrict__ qb, const short* __restrict__ kb,
                const short* __restrict__ vt, const float* __restrict__ adj,
                const float* __restrict__ Wo, const float* __restrict__ bo,
                float* __restrict__ out)
{
    __shared__ short Ps[HC][16 * 40];    // wave-private P scratch, 10.2 KB
    __shared__ float Ws[HC][16];         // w transpose, 0.5 KB
    __shared__ short Cs[16 * 136];       // ctx staging for out-proj, 4.3 KB

    const int tid  = threadIdx.x;
    const int wave = tid >> 6;           // = head h
    const int lane = tid & 63;
    const int l15  = lane & 15;
    const int quad = lane >> 4;
    const int h    = wave;
    const int bt   = blockIdx.y;
    const int qt0  = blockIdx.x * 16;

    const size_t xb = (size_t)bt * NC * DC;
    const size_t ab = (size_t)bt * NC * NC;

    // Q B-frag: B[n=q=l15][k=d=quad*8+j], d>=16 zero (QSCALE folded at proj)
    bf16x8 Bq = (quad < 2)
        ? *(const bf16x8*)&qb[xb + (size_t)(qt0 + l15) * DC + h * HDC + quad * 8]
        : zero8();

    f32x4 Cc = (f32x4){0.f, 0.f, 0.f, 0.f};
    float wacc = 0.f;

    short* Pw = &Ps[wave][0];
    const f32x4 z4 = (f32x4){0.f, 0.f, 0.f, 0.f};

    const short* kbase = &kb[xb + h * HDC + quad * 8];       // valid quad<2
    const short* vbase = &vt[((size_t)bt * DC + h * HDC + l15) * NC];
    const float* abase = &adj[ab + (size_t)(qt0 + l15) * NC + quad * 4];

    for (int jt = 0; jt < NC; jt += 32) {
        // issue all independent loads up front
        bf16x8 Ak0 = (quad < 2) ? *(const bf16x8*)&kbase[(size_t)(jt + l15) * DC]      : zero8();
        bf16x8 Ak1 = (quad < 2) ? *(const bf16x8*)&kbase[(size_t)(jt + 16 + l15) * DC] : zero8();
        bf16x8 Vf  = *(const bf16x8*)&vbase[jt + quad * 8];
        float4 a40 = *(const float4*)&abase[jt];
        float4 a41 = *(const float4*)&abase[jt + 16];

        // S[g]: D[m=key=g*16+quad*4+r][n=q=l15]
        f32x4 S0 = __builtin_amdgcn_mfma_f32_16x16x32_bf16(Ak0, Bq, z4, 0, 0, 0);
        f32x4 S1 = __builtin_amdgcn_mfma_f32_16x16x32_bf16(Ak1, Bq, z4, 0, 0, 0);

        // P^T = exp2(S)*adj -> bf16 -> wave-private LDS [q=l15][key]
        {
            float p0 = EXP2F(S0[0]) * a40.x;
            float p1 = EXP2F(S0[1]) * a40.y;
            float p2 = EXP2F(S0[2]) * a40.z;
            float p3 = EXP2F(S0[3]) * a40.w;
            wacc += (p0 + p1) + (p2 + p3);
            PK2 pk;
            pk.h2[0] = __float22bfloat162_rn(make_float2(p0, p1));
            pk.h2[1] = __float22bfloat162_rn(make_float2(p2, p3));
            *(short4v*)&Pw[l15 * 40 + quad * 4] = pk.s4;
        }
        {
            float p0 = EXP2F(S1[0]) * a41.x;
            float p1 = EXP2F(S1[1]) * a41.y;
            float p2 = EXP2F(S1[2]) * a41.z;
            float p3 = EXP2F(S1[3]) * a41.w;
            wacc += (p0 + p1) + (p2 + p3);
            PK2 pk;
            pk.h2[0] = __float22bfloat162_rn(make_float2(p0, p1));
            pk.h2[1] = __float22bfloat162_rn(make_float2(p2, p3));
            *(short4v*)&Pw[l15 * 40 + 16 + quad * 4] = pk.s4;
        }
        __builtin_amdgcn_wave_barrier();

        // PV: A[m=q=l15][k=key=quad*8+j] spans all 32 keys
        bf16x8 Ap = *(const bf16x8*)&Pw[l15 * 40 + quad * 8];
        Cc = __builtin_amdgcn_mfma_f32_16x16x32_bf16(Ap, Vf, Cc, 0, 0, 0);
        __builtin_amdgcn_wave_barrier();
    }

    // ---- w: reduce across quads, then transpose via tiny LDS ----
    wacc += __shfl_xor(wacc, 16, 64);
    wacc += __shfl_xor(wacc, 32, 64);            // all lanes: w[q = l15]
    if (lane < 16) Ws[wave][lane] = wacc;
    __builtin_amdgcn_wave_barrier();

    // ---- ctx -> LDS bf16 (row = q-local = quad*4+r, col d = l15) ----
#pragma unroll
    for (int r = 0; r < 4; ++r) {
        float den = Ws[wave][quad * 4 + r];
        float rcp = den > 0.f ? 1.f / den : 0.f;
        Cs[(quad * 4 + r) * 136 + h * HDC + l15] = f2bf(Cc[r] * rcp);
    }
    __syncthreads();

    // ---- fused out-projection: out(16x128) = ctx(16x128) @ Wo^T + bo -------
    // wave t handles out cols t*16 .. t*16+15
    f32x4 oacc = (f32x4){0.f, 0.f, 0.f, 0.f};
#pragma unroll
    for (int kk = 0; kk < DC; kk += 32) {
        bf16x8 Ac = *(const bf16x8*)&Cs[l15 * 136 + kk + quad * 8];
        const float* wp = &Wo[(size_t)(wave * 16 + l15) * DC + kk + quad * 8];
        bf16x8 Bf = pack8f(*(const float4*)wp, *(const float4*)(wp + 4));
        oacc = __builtin_amdgcn_mfma_f32_16x16x32_bf16(Ac, Bf, oacc, 0, 0, 0);
    }
    {
        int c = wave * 16 + l15;
        float b = bo[c];
#pragma unroll
        for (int r = 0; r < 4; ++r) {
            int row = qt0 + quad * 4 + r;
            out[((size_t)bt * NC + row) * DC + c] = oacc[r] + b;
        }
    }
}

extern "C" void kernel_launch(void* const* d_in, const int* in_sizes, int n_in,
                              void* d_out, int out_size, void* d_ws, size_t ws_size,
                              hipStream_t stream)
{
    const float* x   = (const float*)d_in[0];
    const float* adj = (const float*)d_in[1];
    const float* Wq  = (const float*)d_in[2];
    const float* bq  = (const float*)d_in[3];
    const float* Wk  = (const float*)d_in[4];
    const float* bk  = (const float*)d_in[5];
    const float* Wv  = (const float*)d_in[6];
    const float* bv  = (const float*)d_in[7];
    const float* Wo  = (const float*)d_in[8];
    const float* bo  = (const float*)d_in[9];
    float* out = (float*)d_out;

    const size_t tok = (size_t)BTC * NC * DC;   // 2,097,152
    short* qbuf = (short*)d_ws;
    short* kbuf = qbuf + tok;
    short* vt   = kbuf + tok;

    dim3 pgrid(256, 3);
    proj_qkv<<<pgrid, 256, 0, stream>>>(x, Wq, bq, Wk, bk, Wv, bv, qbuf, kbuf, vt);

    dim3 agrid(NC / 16, BTC);
    attn_fused<<<agrid, 512, 0, stream>>>(qbuf, kbuf, vt, adj, Wo, bo, out);
}

// Round 8
// 232.301 us; speedup vs baseline: 1.2474x; 1.1312x over previous
//
#include <hip/hip_runtime.h>
#include <hip/hip_bf16.h>

#define BTC 16
#define NC 1024
#define DC 128
#define HC 8
#define HDC 16

typedef __attribute__((ext_vector_type(8)))  short bf16x8;   // 8 bf16 = 4 VGPR
typedef __attribute__((ext_vector_type(4)))  float f32x4;    // 16x16 C/D frag
typedef __attribute__((ext_vector_type(16))) float f32x16;   // 32x32 C/D frag
typedef __attribute__((ext_vector_type(4)))  short short4v;  // 8B pack

#if __has_builtin(__builtin_amdgcn_exp2f)
#define EXP2F(x) __builtin_amdgcn_exp2f(x)
#else
#define EXP2F(x) exp2f(x)
#endif

// q scale: 0.25 (1/sqrt(HD)) * log2(e) -> attention uses exp2 directly
#define QSCALE 0.36067376022224085f

union PK2 { short4v s4; __hip_bfloat162 h2[2]; };
union PK8 { bf16x8 v; short s[8]; __hip_bfloat162 h2[4]; };

static __device__ inline short f2bf(float f) {               // RNE f32->bf16
    unsigned u = __builtin_bit_cast(unsigned, f);
    u += 0x7fffu + ((u >> 16) & 1u);
    return (short)(u >> 16);
}

static __device__ inline bf16x8 pack8f(float4 a, float4 b) {
    PK8 f;
    f.h2[0] = __float22bfloat162_rn(make_float2(a.x, a.y));
    f.h2[1] = __float22bfloat162_rn(make_float2(a.z, a.w));
    f.h2[2] = __float22bfloat162_rn(make_float2(b.x, b.y));
    f.h2[3] = __float22bfloat162_rn(make_float2(b.z, b.w));
    return f.v;
}

// ---------------- qkv projection, fp32 in, bf16 out, LDS-free MFMA ----------
// (unchanged — proven, not the bottleneck)
__global__ __launch_bounds__(256)
void proj_qkv(const float* __restrict__ x,
              const float* __restrict__ Wq, const float* __restrict__ bq,
              const float* __restrict__ Wk, const float* __restrict__ bk,
              const float* __restrict__ Wv, const float* __restrict__ bv,
              short* __restrict__ qo, short* __restrict__ ko, short* __restrict__ vto)
{
    const int y = blockIdx.y;
    const float* W    = (y == 0) ? Wq : (y == 1) ? Wk : Wv;
    const float* bias = (y == 0) ? bq : (y == 1) ? bk : bv;
    const float scale = (y == 0) ? QSCALE : 1.0f;

    const int tid  = threadIdx.x;
    const int wave = tid >> 6;
    const int lane = tid & 63;
    const int l15  = lane & 15;
    const int quad = lane >> 4;
    const int rowA = blockIdx.x * 64 + wave * 16;

    f32x4 acc[8];
#pragma unroll
    for (int t = 0; t < 8; ++t) acc[t] = (f32x4){0.f, 0.f, 0.f, 0.f};

#pragma unroll
    for (int kk = 0; kk < DC; kk += 32) {
        const float* xp = &x[(size_t)(rowA + l15) * DC + kk + quad * 8];
        bf16x8 Af = pack8f(*(const float4*)xp, *(const float4*)(xp + 4));
#pragma unroll
        for (int t = 0; t < 8; ++t) {
            const float* wp = &W[(size_t)(t * 16 + l15) * DC + kk + quad * 8];
            bf16x8 Bf = pack8f(*(const float4*)wp, *(const float4*)(wp + 4));
            acc[t] = __builtin_amdgcn_mfma_f32_16x16x32_bf16(Af, Bf, acc[t], 0, 0, 0);
        }
    }

#pragma unroll
    for (int t = 0; t < 8; ++t) {
        int c = t * 16 + l15;
        float b = bias[c];
#pragma unroll
        for (int r = 0; r < 4; ++r) {
            int row = rowA + quad * 4 + r;
            float val = (acc[t][r] + b) * scale;
            if (y == 2)
                vto[(size_t)(row >> 10) * (DC * NC) + (size_t)c * NC + (row & (NC - 1))] = f2bf(val);
            else
                ((y == 0) ? qo : ko)[(size_t)row * DC + c] = f2bf(val);
        }
    }
}

// ---------------- fused attention + output projection -----------------------
// block = 512 thr = 8 waves = 8 heads; 32 q-rows; grid (32,16) = 512 blocks.
// Plain __launch_bounds__(512): NO min-waves cap — register headroom for
// load hoisting beats forced occupancy (R6/R7 lesson).
// Main loop has NO __syncthreads: adj read straight from global (8 waves
// share each 4 KB tile via L1/L2); P round-trips through wave-private
// XOR-swizzled LDS (conflict-free, R6-verified mapping); w in VALU.
// Per 32-key tile: S^T = K·Q^T (one mfma_32x32x16, R5-verified layouts);
// P = exp2(S)·adj -> bf16; ctx += P·V (2x mfma_16x16x32, s=0,1).
// Epilogue: one __syncthreads, then block-local out = ctx @ Wo^T + bo.
__global__ __launch_bounds__(512)
void attn_fused(const short* __restrict__ qb, const short* __restrict__ kb,
                const short* __restrict__ vt, const float* __restrict__ adj,
                const float* __restrict__ Wo, const float* __restrict__ bo,
                float* __restrict__ out)
{
    __shared__ short Ps[HC][32 * 40];    // wave-private P scratch, 20.5 KB
    __shared__ float Ws[HC][32];         // per-head w, 1 KB
    __shared__ short Cs[32 * 136];       // ctx staging for out-proj, 8.7 KB

    const int tid  = threadIdx.x;
    const int wave = tid >> 6;           // = head h
    const int lane = tid & 63;
    const int l15  = lane & 15;
    const int quad = lane >> 4;
    const int l31  = lane & 31;
    const int lh   = lane >> 5;
    const int h    = wave;
    const int bt   = blockIdx.y;
    const int qt0  = blockIdx.x * 32;

    const size_t xb = (size_t)bt * NC * DC;
    const size_t ab = (size_t)bt * NC * NC;

    // Q B-frag for 32x32x16: B[n=q=l31][k=d=lh*8+j] (QSCALE folded at proj)
    bf16x8 Bq = *(const bf16x8*)&qb[xb + (size_t)(qt0 + l31) * DC + h * HDC + lh * 8];

    f32x4 Cc[2];
    Cc[0] = (f32x4){0.f, 0.f, 0.f, 0.f};
    Cc[1] = (f32x4){0.f, 0.f, 0.f, 0.f};
    float wacc = 0.f;

    short* Pw = &Ps[wave][0];
    const int sw_w = (l31 >> 3) & 3;                 // write-side XOR swizzle
    const f32x16 z16 = {0.f,0.f,0.f,0.f,0.f,0.f,0.f,0.f,
                        0.f,0.f,0.f,0.f,0.f,0.f,0.f,0.f};

    const short* kbase = &kb[xb + h * HDC + lh * 8];
    const short* vbase = &vt[((size_t)bt * DC + h * HDC + l15) * NC];
    const float* abase = &adj[ab + (size_t)(qt0 + l31) * NC + 4 * lh];

    for (int jt = 0; jt < NC; jt += 32) {
        // all independent loads issued up front (compiler hoists/overlaps)
        bf16x8 Kf = *(const bf16x8*)&kbase[(size_t)(jt + l31) * DC];
        bf16x8 Vf = *(const bf16x8*)&vbase[jt + quad * 8];
        float4 a4[4];
#pragma unroll
        for (int rr = 0; rr < 4; ++rr)
            a4[rr] = *(const float4*)&abase[jt + 8 * rr];

        // S^T: D[key = (reg&3) + 8*(reg>>2) + 4*lh][q = l31]
        f32x16 S = __builtin_amdgcn_mfma_f32_32x32x16_bf16(Kf, Bq, z16, 0, 0, 0);

        // P^T = exp2(S^T)*adj -> bf16 -> swizzled wave-private LDS [q][key]
#pragma unroll
        for (int rr = 0; rr < 4; ++rr) {
            float p0 = EXP2F(S[4 * rr + 0]) * a4[rr].x;
            float p1 = EXP2F(S[4 * rr + 1]) * a4[rr].y;
            float p2 = EXP2F(S[4 * rr + 2]) * a4[rr].z;
            float p3 = EXP2F(S[4 * rr + 3]) * a4[rr].w;
            wacc += (p0 + p1) + (p2 + p3);
            PK2 pk;
            pk.h2[0] = __float22bfloat162_rn(make_float2(p0, p1));
            pk.h2[1] = __float22bfloat162_rn(make_float2(p2, p3));
            *(short4v*)&Pw[l31 * 40 + (rr ^ sw_w) * 8 + lh * 4] = pk.s4;
        }
        __builtin_amdgcn_wave_barrier();

        // PV: A[m=q(16)=l15][k=key=quad*8+j], swizzled read
#pragma unroll
        for (int s = 0; s < 2; ++s) {
            int R = s * 16 + l15;
            bf16x8 Ap = *(const bf16x8*)&Pw[R * 40 + (quad ^ ((R >> 3) & 3)) * 8];
            Cc[s] = __builtin_amdgcn_mfma_f32_16x16x32_bf16(Ap, Vf, Cc[s], 0, 0, 0);
        }
        __builtin_amdgcn_wave_barrier();
    }

    // ---- w: lane holds partial for q=l31; finish over lh halves ----
    wacc += __shfl_xor(wacc, 32, 64);
    if (lane < 32) Ws[wave][l31] = wacc;
    __builtin_amdgcn_wave_barrier();

    // ---- ctx -> LDS bf16 (row = s*16+quad*4+r, col = h*16+l15) ----
#pragma unroll
    for (int s = 0; s < 2; ++s)
#pragma unroll
        for (int r = 0; r < 4; ++r) {
            int row = s * 16 + quad * 4 + r;
            float den = Ws[wave][row];
            float rcp = den > 0.f ? 1.f / den : 0.f;
            Cs[row * 136 + h * HDC + l15] = f2bf(Cc[s][r] * rcp);
        }
    __syncthreads();

    // ---- fused out-projection: out(32x128) = ctx(32x128) @ Wo^T + bo -------
    // wave w: rows0 = (w&1)*16 ; col tiles t = (w>>1) and (w>>1)+4
    const int rows0 = (wave & 1) * 16;
    const int tbase = wave >> 1;
    f32x4 oacc[2];
    oacc[0] = (f32x4){0.f, 0.f, 0.f, 0.f};
    oacc[1] = (f32x4){0.f, 0.f, 0.f, 0.f};

#pragma unroll
    for (int kk = 0; kk < DC; kk += 32) {
        bf16x8 Ac = *(const bf16x8*)&Cs[(rows0 + l15) * 136 + kk + quad * 8];
#pragma unroll
        for (int ti = 0; ti < 2; ++ti) {
            int t = tbase + ti * 4;
            const float* wp = &Wo[(size_t)(t * 16 + l15) * DC + kk + quad * 8];
            bf16x8 Bf = pack8f(*(const float4*)wp, *(const float4*)(wp + 4));
            oacc[ti] = __builtin_amdgcn_mfma_f32_16x16x32_bf16(Ac, Bf, oacc[ti], 0, 0, 0);
        }
    }

#pragma unroll
    for (int ti = 0; ti < 2; ++ti) {
        int c = (tbase + ti * 4) * 16 + l15;
        float b = bo[c];
#pragma unroll
        for (int r = 0; r < 4; ++r) {
            int row = qt0 + rows0 + quad * 4 + r;
            out[((size_t)bt * NC + row) * DC + c] = oacc[ti][r] + b;
        }
    }
}

extern "C" void kernel_launch(void* const* d_in, const int* in_sizes, int n_in,
                              void* d_out, int out_size, void* d_ws, size_t ws_size,
                              hipStream_t stream)
{
    const float* x   = (const float*)d_in[0];
    const float* adj = (const float*)d_in[1];
    const float* Wq  = (const float*)d_in[2];
    const float* bq  = (const float*)d_in[3];
    const float* Wk  = (const float*)d_in[4];
    const float* bk  = (const float*)d_in[5];
    const float* Wv  = (const float*)d_in[6];
    const float* bv  = (const float*)d_in[7];
    const float* Wo  = (const float*)d_in[8];
    const float* bo  = (const float*)d_in[9];
    float* out = (float*)d_out;

    const size_t tok = (size_t)BTC * NC * DC;   // 2,097,152
    short* qbuf = (short*)d_ws;
    short* kbuf = qbuf + tok;
    short* vt   = kbuf + tok;

    dim3 pgrid(256, 3);
    proj_qkv<<<pgrid, 256, 0, stream>>>(x, Wq, bq, Wk, bk, Wv, bv, qbuf, kbuf, vt);

    dim3 agrid(NC / 32, BTC);
    attn_fused<<<agrid, 512, 0, stream>>>(qbuf, kbuf, vt, adj, Wo, bo, out);
}